// Round 7
// baseline (60.486 us; speedup 1.0000x reference)
//
#include <hip/hip_runtime.h>
#include <math.h>

// ---------------------------------------------------------------------------
// FraudDetectionHybrid: 4-qubit statevector sim, algebraically collapsed into
// ONE kernel (+ 1KB memset node):
//   encoder -> product state (per-wire 2-vectors)            [per-element]
//   RandomLayer+trainable block -> fixed 16x16 unitary U_post, built PER BLOCK:
//     4 gate-chunks (compile-time constexpr MT19937(42) sequence) built by the
//     4 waves in parallel, combined by two 256-thread complex matmuls in LDS
//   measure <Z_w> -> sign-sums of |U_post s|^2 (ez kept in REGISTERS)
//   grid barrier: per-block partial STORES (unique slots) + one counter RMW
//     per block; LAST block reduces + computes coefs + release-store flag;
//     others poll flag with agent-scope atomic LOADS + s_sleep (no RMW spin)
//   BatchNorm(batch stats) + Linear -> out[b] = sum_w a_w ez[b,w] + c0
//
// R1: MT19937 on device -> scratch serial chain (240us). Constexpr now.
// R2: runtime-indexed sx[16]/sy[16] -> scratch (100us). Templated appliers.
// R3: runtime-indexed GateList kernel arg -> scratch. Constexpr gate seq.
// R4: 4 dispatches -> 2 saved only 1.1us; per-dispatch ~0.5us.
// R5: fixed overhead is only ~5us; kernels were ~21us -> mono worth it.
// R6: RMW spin barrier = cacheline ping-pong across 8 XCDs (+45us). Fixed:
//     read-only flag polling, store-not-add partials, single RMW per block.
// ---------------------------------------------------------------------------

// ==================== compile-time numpy RandomState(42) ====================
struct CGates {
  int kind[64];   // 0=RX 1=RY 2=RZ 3=CNOT 4=CRX 5=H 6=SX
  int w0[64];
  int w1[64];
  int pidx[64];   // >=0: rand_params idx; -1 none; -2 rx0; -3 ry0; -4 rz0; -5 crx0
  int ng;
};

constexpr unsigned int c_mt_next(unsigned int (&mt)[624], int& pos) {
  if (pos >= 624) {
    for (int i = 0; i < 624; ++i) {
      unsigned int y = (mt[i] & 0x80000000u) | (mt[(i + 1) % 624] & 0x7fffffffu);
      unsigned int v = mt[(i + 397) % 624] ^ (y >> 1);
      if (y & 1u) v ^= 0x9908b0dfu;
      mt[i] = v;
    }
    pos = 0;
  }
  unsigned int y = mt[pos++];
  y ^= y >> 11;
  y ^= (y << 7) & 0x9d2c5680u;
  y ^= (y << 15) & 0xefc60000u;
  y ^= y >> 18;
  return y;
}

constexpr CGates make_gates() {
  CGates gl{};
  unsigned int mt[624] = {};
  mt[0] = 42u;
  for (int i = 1; i < 624; ++i)
    mt[i] = 1812433253u * (mt[i - 1] ^ (mt[i - 1] >> 30)) + (unsigned int)i;
  int pos = 624;
  int ng = 0, p = 0;
  for (int op = 0; op < 50; ++op) {
    unsigned int k = c_mt_next(mt, pos) & 3u;   // randint(4): one draw, mask 3
    if (k < 3u) {
      unsigned int w = c_mt_next(mt, pos) & 3u; // wire
      gl.kind[ng] = (int)k; gl.w0[ng] = (int)w; gl.w1[ng] = 0;
      gl.pidx[ng] = p++;
      ++ng;
    } else {
      // choice(4,2,replace=False): Fisher-Yates descending, mask-rejection
      int arr[4] = {0, 1, 2, 3};
      { unsigned int j = c_mt_next(mt, pos) & 3u;
        int t = arr[3]; arr[3] = arr[j]; arr[j] = t; }
      { unsigned int j = c_mt_next(mt, pos) & 3u;
        while (j > 2u) j = c_mt_next(mt, pos) & 3u;
        int t = arr[2]; arr[2] = arr[j]; arr[j] = t; }
      { unsigned int j = c_mt_next(mt, pos) & 1u;
        int t = arr[1]; arr[1] = arr[j]; arr[j] = t; }
      gl.kind[ng] = 3; gl.w0[ng] = arr[0]; gl.w1[ng] = arr[1]; gl.pidx[ng] = -1;
      ++ng;
    }
  }
  // trainable block
  gl.kind[ng] = 0; gl.w0[ng] = 0; gl.w1[ng] = 0; gl.pidx[ng] = -2; ++ng; // RX w0
  gl.kind[ng] = 1; gl.w0[ng] = 1; gl.w1[ng] = 0; gl.pidx[ng] = -3; ++ng; // RY w1
  gl.kind[ng] = 2; gl.w0[ng] = 3; gl.w1[ng] = 0; gl.pidx[ng] = -4; ++ng; // RZ w3
  gl.kind[ng] = 4; gl.w0[ng] = 0; gl.w1[ng] = 2; gl.pidx[ng] = -5; ++ng; // CRX(0,2)
  gl.kind[ng] = 5; gl.w0[ng] = 3; gl.w1[ng] = 0; gl.pidx[ng] = -1; ++ng; // H w3
  gl.kind[ng] = 6; gl.w0[ng] = 2; gl.w1[ng] = 0; gl.pidx[ng] = -1; ++ng; // SX w2
  gl.kind[ng] = 3; gl.w0[ng] = 3; gl.w1[ng] = 0; gl.pidx[ng] = -1; ++ng; // CNOT(3,0)
  gl.ng = ng;
  return gl;
}

inline constexpr CGates GL = make_gates();

// chunk boundaries for the 4-wave parallel build
inline constexpr int CK1 = GL.ng / 4;
inline constexpr int CK2 = GL.ng / 2;
inline constexpr int CK3 = (3 * GL.ng) / 4;

// ================= templated gate appliers (static indices) =================
// wire0 = MSB (bit 3): TB = 8 >> wire.

template <int TB>
__device__ __forceinline__ void ap_rx(float (&sx)[16], float (&sy)[16],
                                      float c, float s) {
#pragma unroll
  for (int i = 0; i < 16; ++i) {
    if (i & TB) continue;
    const int j = i | TB;
    float ax = sx[i], ay = sy[i], bx = sx[j], by = sy[j];
    sx[i] = c * ax + s * by;  sy[i] = c * ay - s * bx;   // a' = c a - i s b
    sx[j] = c * bx + s * ay;  sy[j] = c * by - s * ax;   // b' = -i s a + c b
  }
}

template <int TB>
__device__ __forceinline__ void ap_ry(float (&sx)[16], float (&sy)[16],
                                      float c, float s) {
#pragma unroll
  for (int i = 0; i < 16; ++i) {
    if (i & TB) continue;
    const int j = i | TB;
    float ax = sx[i], ay = sy[i], bx = sx[j], by = sy[j];
    sx[i] = c * ax - s * bx;  sy[i] = c * ay - s * by;   // a' = c a - s b
    sx[j] = s * ax + c * bx;  sy[j] = s * ay + c * by;   // b' = s a + c b
  }
}

template <int TB>
__device__ __forceinline__ void ap_rz(float (&sx)[16], float (&sy)[16],
                                      float c, float s) {
#pragma unroll
  for (int i = 0; i < 16; ++i) {
    if (i & TB) continue;
    const int j = i | TB;
    float ax = sx[i], ay = sy[i], bx = sx[j], by = sy[j];
    sx[i] = c * ax + s * ay;  sy[i] = c * ay - s * ax;   // a' = (c - i s) a
    sx[j] = c * bx - s * by;  sy[j] = c * by + s * bx;   // b' = (c + i s) b
  }
}

template <int TB>
__device__ __forceinline__ void ap_h(float (&sx)[16], float (&sy)[16]) {
  const float r = 0.70710678118654752f;
#pragma unroll
  for (int i = 0; i < 16; ++i) {
    if (i & TB) continue;
    const int j = i | TB;
    float ax = sx[i], ay = sy[i], bx = sx[j], by = sy[j];
    sx[i] = r * (ax + bx);  sy[i] = r * (ay + by);
    sx[j] = r * (ax - bx);  sy[j] = r * (ay - by);
  }
}

template <int TB>
__device__ __forceinline__ void ap_sxg(float (&sx)[16], float (&sy)[16]) {
#pragma unroll
  for (int i = 0; i < 16; ++i) {
    if (i & TB) continue;
    const int j = i | TB;
    float ax = sx[i], ay = sy[i], bx = sx[j], by = sy[j];
    // a' = .5((1+i)a + (1-i)b) ; b' = .5((1-i)a + (1+i)b)
    sx[i] = 0.5f * (ax - ay + bx + by);  sy[i] = 0.5f * (ay + ax + by - bx);
    sx[j] = 0.5f * (ax + ay + bx - by);  sy[j] = 0.5f * (ay - ax + by + bx);
  }
}

template <int CB, int TB>
__device__ __forceinline__ void ap_cnot(float (&sx)[16], float (&sy)[16]) {
#pragma unroll
  for (int i = 0; i < 16; ++i) {
    if (!(i & CB) || (i & TB)) continue;
    const int j = i | TB;
    float tx = sx[i], ty = sy[i];
    sx[i] = sx[j]; sy[i] = sy[j];
    sx[j] = tx;    sy[j] = ty;
  }
}

template <int CB, int TB>
__device__ __forceinline__ void ap_crx(float (&sx)[16], float (&sy)[16],
                                       float c, float s) {
#pragma unroll
  for (int i = 0; i < 16; ++i) {
    if (!(i & CB) || (i & TB)) continue;
    const int j = i | TB;
    float ax = sx[i], ay = sy[i], bx = sx[j], by = sy[j];
    sx[i] = c * ax + s * by;  sy[i] = c * ay - s * bx;
    sx[j] = c * bx + s * ay;  sy[j] = c * by - s * ax;
  }
}

// ============== compile-time-unrolled gate chain over [G, GEND) =============
template <int G, int GEND>
__device__ __forceinline__ void apply_range(
    float (&sx)[16], float (&sy)[16], const float* __restrict__ rp,
    const float* __restrict__ rx0, const float* __restrict__ ry0,
    const float* __restrict__ rz0, const float* __restrict__ crx0) {
  if constexpr (G < GEND) {
    constexpr int kind = GL.kind[G];
    constexpr int TB0 = 8 >> GL.w0[G];
    constexpr int TB1 = 8 >> GL.w1[G];
    constexpr int pi = GL.pidx[G];
    float c = 0.f, s = 0.f;
    if constexpr (kind == 0 || kind == 1 || kind == 2 || kind == 4) {
      float th;
      if constexpr (pi >= 0)       th = rp[pi];
      else if constexpr (pi == -2) th = rx0[0];
      else if constexpr (pi == -3) th = ry0[0];
      else if constexpr (pi == -4) th = rz0[0];
      else                         th = crx0[0];
      __sincosf(0.5f * th, &s, &c);
    }
    if constexpr (kind == 0)      ap_rx<TB0>(sx, sy, c, s);
    else if constexpr (kind == 1) ap_ry<TB0>(sx, sy, c, s);
    else if constexpr (kind == 2) ap_rz<TB0>(sx, sy, c, s);
    else if constexpr (kind == 3) ap_cnot<TB0, TB1>(sx, sy);
    else if constexpr (kind == 4) ap_crx<TB0, TB1>(sx, sy, c, s);
    else if constexpr (kind == 5) ap_h<TB0>(sx, sy);
    else                          ap_sxg<TB0>(sx, sy);
    apply_range<G + 1, GEND>(sx, sy, rp, rx0, ry0, rz0, crx0);
  }
}

// ===================== per-element ez, split in two phases ==================
__device__ __forceinline__ void phase1(const float* __restrict__ features,
                                       long long b, float (&t01x)[4],
                                       float (&t01y)[4], float (&t23x)[4],
                                       float (&t23y)[4]) {
  const float4* fp = (const float4*)(features + b * 16);
  float4 F0 = fp[0], F1 = fp[1], F2 = fp[2], F3 = fp[3];
  float L0[4] = {F0.x, F0.y, F0.z, F0.w};
  float L1[4] = {F1.x, F1.y, F1.z, F1.w};
  float L2[4] = {F2.x, F2.y, F2.z, F2.w};
  float L3[4] = {F3.x, F3.y, F3.z, F3.w};
  float vax[4], vay[4], vbx[4], vby[4];
#pragma unroll
  for (int w = 0; w < 4; ++w) {
    // per-wire |0> column of RY(L3) RX(L2) RZ(L1) RY(L0)
    float s0, c0; __sincosf(0.5f * L0[w], &s0, &c0);
    float s1, c1; __sincosf(0.5f * L1[w], &s1, &c1);
    float s2, c2; __sincosf(0.5f * L2[w], &s2, &c2);
    float s3, c3; __sincosf(0.5f * L3[w], &s3, &c3);
    float ax = c0 * c1, ay = -c0 * s1;       // after RZ
    float bx = s0 * c1, by = s0 * s1;
    float a2x = c2 * ax + s2 * by, a2y = c2 * ay - s2 * bx;   // after RX
    float b2x = s2 * ay + c2 * bx, b2y = -s2 * ax + c2 * by;
    vax[w] = c3 * a2x - s3 * b2x; vay[w] = c3 * a2y - s3 * b2y;  // after RY
    vbx[w] = s3 * a2x + c3 * b2x; vby[w] = s3 * a2y + c3 * b2y;
  }
  // pairwise tensor products (wire0 = MSB)
  t01x[0] = vax[0] * vax[1] - vay[0] * vay[1]; t01y[0] = vax[0] * vay[1] + vay[0] * vax[1];
  t01x[1] = vax[0] * vbx[1] - vay[0] * vby[1]; t01y[1] = vax[0] * vby[1] + vay[0] * vbx[1];
  t01x[2] = vbx[0] * vax[1] - vby[0] * vay[1]; t01y[2] = vbx[0] * vay[1] + vby[0] * vax[1];
  t01x[3] = vbx[0] * vbx[1] - vby[0] * vby[1]; t01y[3] = vbx[0] * vby[1] + vby[0] * vbx[1];
  t23x[0] = vax[2] * vax[3] - vay[2] * vay[3]; t23y[0] = vax[2] * vay[3] + vay[2] * vax[3];
  t23x[1] = vax[2] * vbx[3] - vay[2] * vby[3]; t23y[1] = vax[2] * vby[3] + vay[2] * vbx[3];
  t23x[2] = vbx[2] * vax[3] - vby[2] * vay[3]; t23y[2] = vbx[2] * vay[3] + vby[2] * vax[3];
  t23x[3] = vbx[2] * vbx[3] - vby[2] * vby[3]; t23y[3] = vbx[2] * vby[3] + vby[2] * vbx[3];
}

__device__ __forceinline__ void phase2(const float2* __restrict__ Uld,
                                       const float (&t01x)[4], const float (&t01y)[4],
                                       const float (&t23x)[4], const float (&t23y)[4],
                                       float (&ez)[4]) {
  float sx[16], sy[16];
#pragma unroll
  for (int i = 0; i < 16; ++i) {
    int a = i >> 2, c = i & 3;
    sx[i] = t01x[a] * t23x[c] - t01y[a] * t23y[c];
    sy[i] = t01x[a] * t23y[c] + t01y[a] * t23x[c];
  }
  float e0 = 0.f, e1 = 0.f, e2 = 0.f, e3 = 0.f;
#pragma unroll
  for (int i = 0; i < 16; ++i) {
    float ax = 0.f, ay = 0.f;
#pragma unroll
    for (int j = 0; j < 16; ++j) {
      float2 u = Uld[i * 16 + j];
      ax += u.x * sx[j] - u.y * sy[j];
      ay += u.x * sy[j] + u.y * sx[j];
    }
    float p = ax * ax + ay * ay;
    e0 += (i & 8) ? -p : p;
    e1 += (i & 4) ? -p : p;
    e2 += (i & 2) ? -p : p;
    e3 += (i & 1) ? -p : p;
  }
  ez[0] = e0; ez[1] = e1; ez[2] = e2; ez[3] = e3;
}

// ============================= the single kernel ============================
// ws float layout: partials[nblk*8] at 0; counter at F_CTR; coefs at F_COEF;
// flag at F_FLAG. Only [F_CTR .. F_FLAG] region is memset to 0 per call.
#define F_CTR  4096
#define F_COEF 4160
#define F_FLAG 4224

__global__ __launch_bounds__(256, 2) void mono_kernel(
    const float* __restrict__ features, const float* __restrict__ rand_params,
    const float* __restrict__ rx0, const float* __restrict__ ry0,
    const float* __restrict__ rz0, const float* __restrict__ crx0,
    const float* __restrict__ gamma, const float* __restrict__ beta,
    const float* __restrict__ W, const float* __restrict__ bias,
    float* __restrict__ acc, float* __restrict__ out, int B, int nblk,
    float invB) {
  __shared__ float2 chunks[4][256];   // 8 KB: per-wave partial products
  __shared__ float2 comb[2][256];     // 4 KB: C10, C32
  __shared__ float wred[4][8];
  __shared__ float coefs[5];
  __shared__ int is_last;

  int tid = threadIdx.x;
  long long b = (long long)blockIdx.x * 256 + tid;
  bool valid = b < B;

  // ---- phase 1: encoder product state (all threads) ----
  float t01x[4], t01y[4], t23x[4], t23y[4];
  if (valid) phase1(features, b, t01x, t01y, t23x, t23y);

  // ---- U-build: wave wv builds gate-chunk wv on lanes 0..15 ----
  int wv = tid >> 6, lane = tid & 63;
  if (lane < 16) {
    float sx[16], sy[16];
#pragma unroll
    for (int i = 0; i < 16; ++i) { sx[i] = (i == lane) ? 1.f : 0.f; sy[i] = 0.f; }
    if (wv == 0)      apply_range<0,   CK1  >(sx, sy, rand_params, rx0, ry0, rz0, crx0);
    else if (wv == 1) apply_range<CK1, CK2  >(sx, sy, rand_params, rx0, ry0, rz0, crx0);
    else if (wv == 2) apply_range<CK2, CK3  >(sx, sy, rand_params, rx0, ry0, rz0, crx0);
    else              apply_range<CK3, GL.ng>(sx, sy, rand_params, rx0, ry0, rz0, crx0);
#pragma unroll
    for (int i = 0; i < 16; ++i)
      chunks[wv][i * 16 + lane] = make_float2(sx[i], sy[i]);
  }
  __syncthreads();

  // ---- combine round 1: C10 = G1*G0, C32 = G3*G2 (one element/thread) ----
  {
    int r = tid >> 4, c = tid & 15;
    float xr = 0.f, xi = 0.f, yr = 0.f, yi = 0.f;
#pragma unroll
    for (int k = 0; k < 16; ++k) {
      float2 g1 = chunks[1][r * 16 + k], g0 = chunks[0][k * 16 + c];
      xr += g1.x * g0.x - g1.y * g0.y;  xi += g1.x * g0.y + g1.y * g0.x;
      float2 g3 = chunks[3][r * 16 + k], g2 = chunks[2][k * 16 + c];
      yr += g3.x * g2.x - g3.y * g2.y;  yi += g3.x * g2.y + g3.y * g2.x;
    }
    comb[0][r * 16 + c] = make_float2(xr, xi);
    comb[1][r * 16 + c] = make_float2(yr, yi);
  }
  __syncthreads();

  // ---- combine round 2: U = C32*C10 -> chunks[0] ----
  {
    int r = tid >> 4, c = tid & 15;
    float ur = 0.f, ui = 0.f;
#pragma unroll
    for (int k = 0; k < 16; ++k) {
      float2 a = comb[1][r * 16 + k], d = comb[0][k * 16 + c];
      ur += a.x * d.x - a.y * d.y;
      ui += a.x * d.y + a.y * d.x;
    }
    chunks[0][r * 16 + c] = make_float2(ur, ui);
  }
  __syncthreads();

  // ---- phase 2: matvec + <Z> (ez stays in registers) ----
  float ez[4] = {0.f, 0.f, 0.f, 0.f};
  if (valid) phase2(&chunks[0][0], t01x, t01y, t23x, t23y, ez);

  // ---- block reduction of [ez, ez^2] ----
  float q[8] = {ez[0], ez[1], ez[2], ez[3],
                ez[0] * ez[0], ez[1] * ez[1], ez[2] * ez[2], ez[3] * ez[3]};
#pragma unroll
  for (int off = 32; off; off >>= 1)
#pragma unroll
    for (int k = 0; k < 8; ++k) q[k] += __shfl_down(q[k], off, 64);
  if ((tid & 63) == 0)
#pragma unroll
    for (int k = 0; k < 8; ++k) wred[wv][k] = q[k];
  __syncthreads();

  // ---- publish block partials: plain agent-scope stores, unique slots ----
  unsigned int* cnt  = (unsigned int*)(acc + F_CTR);
  unsigned int* flag = (unsigned int*)(acc + F_FLAG);
  float* gcoef = acc + F_COEF;
  if (tid < 8) {
    float s = wred[0][tid] + wred[1][tid] + wred[2][tid] + wred[3][tid];
    __hip_atomic_store(&acc[(size_t)blockIdx.x * 8 + tid], s,
                       __ATOMIC_RELAXED, __HIP_MEMORY_SCOPE_AGENT);
    __threadfence();
  }
  __syncthreads();

  // ---- single RMW per block: arrival counter; detect last arriver ----
  if (tid == 0) {
    unsigned int prev = atomicAdd(cnt, 1u);
    is_last = (prev == (unsigned int)nblk - 1u) ? 1 : 0;
  }
  __syncthreads();

  if (is_last) {
    // last block: reduce all partials (coherent atomic loads), compute coefs
    float r[8] = {0.f, 0.f, 0.f, 0.f, 0.f, 0.f, 0.f, 0.f};
    for (int i = tid; i < nblk; i += 256)
#pragma unroll
      for (int k = 0; k < 8; ++k)
        r[k] += __hip_atomic_load(&acc[(size_t)i * 8 + k], __ATOMIC_RELAXED,
                                  __HIP_MEMORY_SCOPE_AGENT);
#pragma unroll
    for (int off = 32; off; off >>= 1)
#pragma unroll
      for (int k = 0; k < 8; ++k) r[k] += __shfl_down(r[k], off, 64);
    if ((tid & 63) == 0)
#pragma unroll
      for (int k = 0; k < 8; ++k) wred[wv][k] = r[k];
    __syncthreads();
    if (tid == 0) {
      float c0 = bias[0];
#pragma unroll
      for (int w = 0; w < 4; ++w) {
        float Sw = wred[0][w] + wred[1][w] + wred[2][w] + wred[3][w];
        float Qw = wred[0][4 + w] + wred[1][4 + w] + wred[2][4 + w] + wred[3][4 + w];
        float mu = Sw * invB;
        float var = Qw * invB - mu * mu;
        float inv = rsqrtf(var + 1e-5f);
        float cw = W[w] * gamma[w] * inv;
        coefs[w] = cw;
        c0 += W[w] * (beta[w] - gamma[w] * mu * inv);
        __hip_atomic_store(&gcoef[w], cw, __ATOMIC_RELAXED,
                           __HIP_MEMORY_SCOPE_AGENT);
      }
      coefs[4] = c0;
      __hip_atomic_store(&gcoef[4], c0, __ATOMIC_RELAXED,
                         __HIP_MEMORY_SCOPE_AGENT);
      __threadfence();
      __hip_atomic_store(flag, 1u, __ATOMIC_RELEASE, __HIP_MEMORY_SCOPE_AGENT);
    }
  } else {
    // other blocks: read-only flag poll (no cacheline ownership), then coefs
    if (tid == 0) {
      while (__hip_atomic_load(flag, __ATOMIC_ACQUIRE,
                               __HIP_MEMORY_SCOPE_AGENT) == 0u)
        __builtin_amdgcn_s_sleep(8);
#pragma unroll
      for (int w = 0; w < 5; ++w)
        coefs[w] = __hip_atomic_load(&gcoef[w], __ATOMIC_RELAXED,
                                     __HIP_MEMORY_SCOPE_AGENT);
    }
  }
  __syncthreads();

  // ---- output ----
  if (valid)
    out[b] = coefs[4] + coefs[0] * ez[0] + coefs[1] * ez[1] +
             coefs[2] * ez[2] + coefs[3] * ez[3];
}

// ================================ launch ====================================
extern "C" void kernel_launch(void* const* d_in, const int* in_sizes, int n_in,
                              void* d_out, int out_size, void* d_ws, size_t ws_size,
                              hipStream_t stream) {
  const float* features    = (const float*)d_in[0];
  const float* rand_params = (const float*)d_in[1];
  const float* rx0         = (const float*)d_in[2];
  const float* ry0         = (const float*)d_in[3];
  const float* rz0         = (const float*)d_in[4];
  const float* crx0        = (const float*)d_in[5];
  const float* gamma       = (const float*)d_in[6];
  const float* beta        = (const float*)d_in[7];
  const float* W           = (const float*)d_in[8];
  const float* bias        = (const float*)d_in[9];
  float* out = (float*)d_out;

  int B = in_sizes[0] / 16;
  int nblk = (B + 255) / 256;   // 512 blocks @ 2/CU: co-resident on 256 CUs

  float* acc = (float*)d_ws;    // partials + counter + coefs + flag
  // zero only counter/coefs/flag region (floats F_CTR..F_FLAG inclusive)
  hipMemsetAsync((char*)d_ws + F_CTR * 4, 0, (F_FLAG - F_CTR + 64) * 4, stream);

  mono_kernel<<<nblk, 256, 0, stream>>>(
      features, rand_params, rx0, ry0, rz0, crx0, gamma, beta, W, bias,
      acc, out, B, nblk, 1.0f / (float)B);
}

// Round 8
// 31.780 us; speedup vs baseline: 1.9033x; 1.9033x over previous
//
#include <hip/hip_runtime.h>
#include <math.h>

// ---------------------------------------------------------------------------
// FraudDetectionHybrid: 4-qubit statevector sim, algebraically collapsed into
// ONE kernel (+ 8.7KB memset node):
//   encoder -> product state; constexpr-MT19937(42) gate seq -> U_post built
//   per block (4 waves in parallel + 2 LDS combine matmuls); <Z_w> in regs;
//   grid barrier with ZERO cache-maintenance ops:
//     all cross-block traffic = RELAXED agent-scope atomics (L2-bypass,
//     served at coherent Infinity Cache); ordering = s_waitcnt vmcnt(0)
//     (completion-at-IC) instead of __threadfence (no buffer_wbl2);
//     64 flag copies on separate lines, <=8 pollers each, s_sleep backoff.
//   BatchNorm(batch stats) + Linear -> out[b] = sum_w a_w ez[b,w] + c0
//
// R1: device MT19937 -> scratch chain (240us). R2: runtime-indexed amp arrays
// -> scratch (100us). R3: runtime-indexed gate args -> scratch. R4: dispatch
// count barely matters (~0.5us each). R5: mono-kernel worth it if barrier ok.
// R6: RMW-spin barrier = 55us. R7: load-spin + s_sleep ALSO 55us -> cost is
// poll-rate-insensitive => suspect per-thread __threadfence (4096 L2
// writebacks) and single-address serialization. Both eliminated here.
// ---------------------------------------------------------------------------

// ==================== compile-time numpy RandomState(42) ====================
struct CGates {
  int kind[64];   // 0=RX 1=RY 2=RZ 3=CNOT 4=CRX 5=H 6=SX
  int w0[64];
  int w1[64];
  int pidx[64];   // >=0: rand_params idx; -1 none; -2 rx0; -3 ry0; -4 rz0; -5 crx0
  int ng;
};

constexpr unsigned int c_mt_next(unsigned int (&mt)[624], int& pos) {
  if (pos >= 624) {
    for (int i = 0; i < 624; ++i) {
      unsigned int y = (mt[i] & 0x80000000u) | (mt[(i + 1) % 624] & 0x7fffffffu);
      unsigned int v = mt[(i + 397) % 624] ^ (y >> 1);
      if (y & 1u) v ^= 0x9908b0dfu;
      mt[i] = v;
    }
    pos = 0;
  }
  unsigned int y = mt[pos++];
  y ^= y >> 11;
  y ^= (y << 7) & 0x9d2c5680u;
  y ^= (y << 15) & 0xefc60000u;
  y ^= y >> 18;
  return y;
}

constexpr CGates make_gates() {
  CGates gl{};
  unsigned int mt[624] = {};
  mt[0] = 42u;
  for (int i = 1; i < 624; ++i)
    mt[i] = 1812433253u * (mt[i - 1] ^ (mt[i - 1] >> 30)) + (unsigned int)i;
  int pos = 624;
  int ng = 0, p = 0;
  for (int op = 0; op < 50; ++op) {
    unsigned int k = c_mt_next(mt, pos) & 3u;   // randint(4): one draw, mask 3
    if (k < 3u) {
      unsigned int w = c_mt_next(mt, pos) & 3u; // wire
      gl.kind[ng] = (int)k; gl.w0[ng] = (int)w; gl.w1[ng] = 0;
      gl.pidx[ng] = p++;
      ++ng;
    } else {
      // choice(4,2,replace=False): Fisher-Yates descending, mask-rejection
      int arr[4] = {0, 1, 2, 3};
      { unsigned int j = c_mt_next(mt, pos) & 3u;
        int t = arr[3]; arr[3] = arr[j]; arr[j] = t; }
      { unsigned int j = c_mt_next(mt, pos) & 3u;
        while (j > 2u) j = c_mt_next(mt, pos) & 3u;
        int t = arr[2]; arr[2] = arr[j]; arr[j] = t; }
      { unsigned int j = c_mt_next(mt, pos) & 1u;
        int t = arr[1]; arr[1] = arr[j]; arr[j] = t; }
      gl.kind[ng] = 3; gl.w0[ng] = arr[0]; gl.w1[ng] = arr[1]; gl.pidx[ng] = -1;
      ++ng;
    }
  }
  // trainable block
  gl.kind[ng] = 0; gl.w0[ng] = 0; gl.w1[ng] = 0; gl.pidx[ng] = -2; ++ng; // RX w0
  gl.kind[ng] = 1; gl.w0[ng] = 1; gl.w1[ng] = 0; gl.pidx[ng] = -3; ++ng; // RY w1
  gl.kind[ng] = 2; gl.w0[ng] = 3; gl.w1[ng] = 0; gl.pidx[ng] = -4; ++ng; // RZ w3
  gl.kind[ng] = 4; gl.w0[ng] = 0; gl.w1[ng] = 2; gl.pidx[ng] = -5; ++ng; // CRX(0,2)
  gl.kind[ng] = 5; gl.w0[ng] = 3; gl.w1[ng] = 0; gl.pidx[ng] = -1; ++ng; // H w3
  gl.kind[ng] = 6; gl.w0[ng] = 2; gl.w1[ng] = 0; gl.pidx[ng] = -1; ++ng; // SX w2
  gl.kind[ng] = 3; gl.w0[ng] = 3; gl.w1[ng] = 0; gl.pidx[ng] = -1; ++ng; // CNOT(3,0)
  gl.ng = ng;
  return gl;
}

inline constexpr CGates GL = make_gates();

// chunk boundaries for the 4-wave parallel build
inline constexpr int CK1 = GL.ng / 4;
inline constexpr int CK2 = GL.ng / 2;
inline constexpr int CK3 = (3 * GL.ng) / 4;

// ================= templated gate appliers (static indices) =================
// wire0 = MSB (bit 3): TB = 8 >> wire.

template <int TB>
__device__ __forceinline__ void ap_rx(float (&sx)[16], float (&sy)[16],
                                      float c, float s) {
#pragma unroll
  for (int i = 0; i < 16; ++i) {
    if (i & TB) continue;
    const int j = i | TB;
    float ax = sx[i], ay = sy[i], bx = sx[j], by = sy[j];
    sx[i] = c * ax + s * by;  sy[i] = c * ay - s * bx;   // a' = c a - i s b
    sx[j] = c * bx + s * ay;  sy[j] = c * by - s * ax;   // b' = -i s a + c b
  }
}

template <int TB>
__device__ __forceinline__ void ap_ry(float (&sx)[16], float (&sy)[16],
                                      float c, float s) {
#pragma unroll
  for (int i = 0; i < 16; ++i) {
    if (i & TB) continue;
    const int j = i | TB;
    float ax = sx[i], ay = sy[i], bx = sx[j], by = sy[j];
    sx[i] = c * ax - s * bx;  sy[i] = c * ay - s * by;   // a' = c a - s b
    sx[j] = s * ax + c * bx;  sy[j] = s * ay + c * by;   // b' = s a + c b
  }
}

template <int TB>
__device__ __forceinline__ void ap_rz(float (&sx)[16], float (&sy)[16],
                                      float c, float s) {
#pragma unroll
  for (int i = 0; i < 16; ++i) {
    if (i & TB) continue;
    const int j = i | TB;
    float ax = sx[i], ay = sy[i], bx = sx[j], by = sy[j];
    sx[i] = c * ax + s * ay;  sy[i] = c * ay - s * ax;   // a' = (c - i s) a
    sx[j] = c * bx - s * by;  sy[j] = c * by + s * bx;   // b' = (c + i s) b
  }
}

template <int TB>
__device__ __forceinline__ void ap_h(float (&sx)[16], float (&sy)[16]) {
  const float r = 0.70710678118654752f;
#pragma unroll
  for (int i = 0; i < 16; ++i) {
    if (i & TB) continue;
    const int j = i | TB;
    float ax = sx[i], ay = sy[i], bx = sx[j], by = sy[j];
    sx[i] = r * (ax + bx);  sy[i] = r * (ay + by);
    sx[j] = r * (ax - bx);  sy[j] = r * (ay - by);
  }
}

template <int TB>
__device__ __forceinline__ void ap_sxg(float (&sx)[16], float (&sy)[16]) {
#pragma unroll
  for (int i = 0; i < 16; ++i) {
    if (i & TB) continue;
    const int j = i | TB;
    float ax = sx[i], ay = sy[i], bx = sx[j], by = sy[j];
    // a' = .5((1+i)a + (1-i)b) ; b' = .5((1-i)a + (1+i)b)
    sx[i] = 0.5f * (ax - ay + bx + by);  sy[i] = 0.5f * (ay + ax + by - bx);
    sx[j] = 0.5f * (ax + ay + bx - by);  sy[j] = 0.5f * (ay - ax + by + bx);
  }
}

template <int CB, int TB>
__device__ __forceinline__ void ap_cnot(float (&sx)[16], float (&sy)[16]) {
#pragma unroll
  for (int i = 0; i < 16; ++i) {
    if (!(i & CB) || (i & TB)) continue;
    const int j = i | TB;
    float tx = sx[i], ty = sy[i];
    sx[i] = sx[j]; sy[i] = sy[j];
    sx[j] = tx;    sy[j] = ty;
  }
}

template <int CB, int TB>
__device__ __forceinline__ void ap_crx(float (&sx)[16], float (&sy)[16],
                                       float c, float s) {
#pragma unroll
  for (int i = 0; i < 16; ++i) {
    if (!(i & CB) || (i & TB)) continue;
    const int j = i | TB;
    float ax = sx[i], ay = sy[i], bx = sx[j], by = sy[j];
    sx[i] = c * ax + s * by;  sy[i] = c * ay - s * bx;
    sx[j] = c * bx + s * ay;  sy[j] = c * by - s * ax;
  }
}

// ============== compile-time-unrolled gate chain over [G, GEND) =============
template <int G, int GEND>
__device__ __forceinline__ void apply_range(
    float (&sx)[16], float (&sy)[16], const float* __restrict__ rp,
    const float* __restrict__ rx0, const float* __restrict__ ry0,
    const float* __restrict__ rz0, const float* __restrict__ crx0) {
  if constexpr (G < GEND) {
    constexpr int kind = GL.kind[G];
    constexpr int TB0 = 8 >> GL.w0[G];
    constexpr int TB1 = 8 >> GL.w1[G];
    constexpr int pi = GL.pidx[G];
    float c = 0.f, s = 0.f;
    if constexpr (kind == 0 || kind == 1 || kind == 2 || kind == 4) {
      float th;
      if constexpr (pi >= 0)       th = rp[pi];
      else if constexpr (pi == -2) th = rx0[0];
      else if constexpr (pi == -3) th = ry0[0];
      else if constexpr (pi == -4) th = rz0[0];
      else                         th = crx0[0];
      __sincosf(0.5f * th, &s, &c);
    }
    if constexpr (kind == 0)      ap_rx<TB0>(sx, sy, c, s);
    else if constexpr (kind == 1) ap_ry<TB0>(sx, sy, c, s);
    else if constexpr (kind == 2) ap_rz<TB0>(sx, sy, c, s);
    else if constexpr (kind == 3) ap_cnot<TB0, TB1>(sx, sy);
    else if constexpr (kind == 4) ap_crx<TB0, TB1>(sx, sy, c, s);
    else if constexpr (kind == 5) ap_h<TB0>(sx, sy);
    else                          ap_sxg<TB0>(sx, sy);
    apply_range<G + 1, GEND>(sx, sy, rp, rx0, ry0, rz0, crx0);
  }
}

// ===================== per-element ez, split in two phases ==================
__device__ __forceinline__ void phase1(const float* __restrict__ features,
                                       long long b, float (&t01x)[4],
                                       float (&t01y)[4], float (&t23x)[4],
                                       float (&t23y)[4]) {
  const float4* fp = (const float4*)(features + b * 16);
  float4 F0 = fp[0], F1 = fp[1], F2 = fp[2], F3 = fp[3];
  float L0[4] = {F0.x, F0.y, F0.z, F0.w};
  float L1[4] = {F1.x, F1.y, F1.z, F1.w};
  float L2[4] = {F2.x, F2.y, F2.z, F2.w};
  float L3[4] = {F3.x, F3.y, F3.z, F3.w};
  float vax[4], vay[4], vbx[4], vby[4];
#pragma unroll
  for (int w = 0; w < 4; ++w) {
    // per-wire |0> column of RY(L3) RX(L2) RZ(L1) RY(L0)
    float s0, c0; __sincosf(0.5f * L0[w], &s0, &c0);
    float s1, c1; __sincosf(0.5f * L1[w], &s1, &c1);
    float s2, c2; __sincosf(0.5f * L2[w], &s2, &c2);
    float s3, c3; __sincosf(0.5f * L3[w], &s3, &c3);
    float ax = c0 * c1, ay = -c0 * s1;       // after RZ
    float bx = s0 * c1, by = s0 * s1;
    float a2x = c2 * ax + s2 * by, a2y = c2 * ay - s2 * bx;   // after RX
    float b2x = s2 * ay + c2 * bx, b2y = -s2 * ax + c2 * by;
    vax[w] = c3 * a2x - s3 * b2x; vay[w] = c3 * a2y - s3 * b2y;  // after RY
    vbx[w] = s3 * a2x + c3 * b2x; vby[w] = s3 * a2y + c3 * b2y;
  }
  // pairwise tensor products (wire0 = MSB)
  t01x[0] = vax[0] * vax[1] - vay[0] * vay[1]; t01y[0] = vax[0] * vay[1] + vay[0] * vax[1];
  t01x[1] = vax[0] * vbx[1] - vay[0] * vby[1]; t01y[1] = vax[0] * vby[1] + vay[0] * vbx[1];
  t01x[2] = vbx[0] * vax[1] - vby[0] * vay[1]; t01y[2] = vbx[0] * vay[1] + vby[0] * vax[1];
  t01x[3] = vbx[0] * vbx[1] - vby[0] * vby[1]; t01y[3] = vbx[0] * vby[1] + vby[0] * vbx[1];
  t23x[0] = vax[2] * vax[3] - vay[2] * vay[3]; t23y[0] = vax[2] * vay[3] + vay[2] * vax[3];
  t23x[1] = vax[2] * vbx[3] - vay[2] * vby[3]; t23y[1] = vax[2] * vby[3] + vay[2] * vbx[3];
  t23x[2] = vbx[2] * vax[3] - vby[2] * vay[3]; t23y[2] = vbx[2] * vay[3] + vby[2] * vax[3];
  t23x[3] = vbx[2] * vbx[3] - vby[2] * vby[3]; t23y[3] = vbx[2] * vby[3] + vby[2] * vbx[3];
}

__device__ __forceinline__ void phase2(const float2* __restrict__ Uld,
                                       const float (&t01x)[4], const float (&t01y)[4],
                                       const float (&t23x)[4], const float (&t23y)[4],
                                       float (&ez)[4]) {
  float sx[16], sy[16];
#pragma unroll
  for (int i = 0; i < 16; ++i) {
    int a = i >> 2, c = i & 3;
    sx[i] = t01x[a] * t23x[c] - t01y[a] * t23y[c];
    sy[i] = t01x[a] * t23y[c] + t01y[a] * t23x[c];
  }
  float e0 = 0.f, e1 = 0.f, e2 = 0.f, e3 = 0.f;
#pragma unroll
  for (int i = 0; i < 16; ++i) {
    float ax = 0.f, ay = 0.f;
#pragma unroll
    for (int j = 0; j < 16; ++j) {
      float2 u = Uld[i * 16 + j];
      ax += u.x * sx[j] - u.y * sy[j];
      ay += u.x * sy[j] + u.y * sx[j];
    }
    float p = ax * ax + ay * ay;
    e0 += (i & 8) ? -p : p;
    e1 += (i & 4) ? -p : p;
    e2 += (i & 2) ? -p : p;
    e3 += (i & 1) ? -p : p;
  }
  ez[0] = e0; ez[1] = e1; ez[2] = e2; ez[3] = e3;
}

// ============================= the single kernel ============================
// ws float layout: partials[nblk*8] at 0; counter @F_CTR; coefs @F_COEF
// (own 128B line); 64 flags @F_FLAG + i*32 (128B stride). memset zeroes
// [F_CTR, F_FLAG+64*32) each call.
#define F_CTR  4096
#define F_COEF 4128
#define F_FLAG 4224
#define RLX __ATOMIC_RELAXED
#define AGT __HIP_MEMORY_SCOPE_AGENT

__global__ __launch_bounds__(256, 2) void mono_kernel(
    const float* __restrict__ features, const float* __restrict__ rand_params,
    const float* __restrict__ rx0, const float* __restrict__ ry0,
    const float* __restrict__ rz0, const float* __restrict__ crx0,
    const float* __restrict__ gamma, const float* __restrict__ beta,
    const float* __restrict__ W, const float* __restrict__ bias,
    float* __restrict__ acc, float* __restrict__ out, int B, int nblk,
    float invB) {
  __shared__ float2 chunks[4][256];   // 8 KB: per-wave partial products
  __shared__ float2 comb[2][256];     // 4 KB: C10, C32
  __shared__ float wred[4][8];
  __shared__ float coefs[5];
  __shared__ int is_last;

  int tid = threadIdx.x;
  long long b = (long long)blockIdx.x * 256 + tid;
  bool valid = b < B;

  // ---- phase 1: encoder product state (all threads) ----
  float t01x[4], t01y[4], t23x[4], t23y[4];
  if (valid) phase1(features, b, t01x, t01y, t23x, t23y);

  // ---- U-build: wave wv builds gate-chunk wv on lanes 0..15 ----
  int wv = tid >> 6, lane = tid & 63;
  if (lane < 16) {
    float sx[16], sy[16];
#pragma unroll
    for (int i = 0; i < 16; ++i) { sx[i] = (i == lane) ? 1.f : 0.f; sy[i] = 0.f; }
    if (wv == 0)      apply_range<0,   CK1  >(sx, sy, rand_params, rx0, ry0, rz0, crx0);
    else if (wv == 1) apply_range<CK1, CK2  >(sx, sy, rand_params, rx0, ry0, rz0, crx0);
    else if (wv == 2) apply_range<CK2, CK3  >(sx, sy, rand_params, rx0, ry0, rz0, crx0);
    else              apply_range<CK3, GL.ng>(sx, sy, rand_params, rx0, ry0, rz0, crx0);
#pragma unroll
    for (int i = 0; i < 16; ++i)
      chunks[wv][i * 16 + lane] = make_float2(sx[i], sy[i]);
  }
  __syncthreads();

  // ---- combine round 1: C10 = G1*G0, C32 = G3*G2 (one element/thread) ----
  {
    int r = tid >> 4, c = tid & 15;
    float xr = 0.f, xi = 0.f, yr = 0.f, yi = 0.f;
#pragma unroll
    for (int k = 0; k < 16; ++k) {
      float2 g1 = chunks[1][r * 16 + k], g0 = chunks[0][k * 16 + c];
      xr += g1.x * g0.x - g1.y * g0.y;  xi += g1.x * g0.y + g1.y * g0.x;
      float2 g3 = chunks[3][r * 16 + k], g2 = chunks[2][k * 16 + c];
      yr += g3.x * g2.x - g3.y * g2.y;  yi += g3.x * g2.y + g3.y * g2.x;
    }
    comb[0][r * 16 + c] = make_float2(xr, xi);
    comb[1][r * 16 + c] = make_float2(yr, yi);
  }
  __syncthreads();

  // ---- combine round 2: U = C32*C10 -> chunks[0] ----
  {
    int r = tid >> 4, c = tid & 15;
    float ur = 0.f, ui = 0.f;
#pragma unroll
    for (int k = 0; k < 16; ++k) {
      float2 a = comb[1][r * 16 + k], d = comb[0][k * 16 + c];
      ur += a.x * d.x - a.y * d.y;
      ui += a.x * d.y + a.y * d.x;
    }
    chunks[0][r * 16 + c] = make_float2(ur, ui);
  }
  __syncthreads();

  // ---- phase 2: matvec + <Z> (ez stays in registers) ----
  float ez[4] = {0.f, 0.f, 0.f, 0.f};
  if (valid) phase2(&chunks[0][0], t01x, t01y, t23x, t23y, ez);

  // ---- block reduction of [ez, ez^2] ----
  float q[8] = {ez[0], ez[1], ez[2], ez[3],
                ez[0] * ez[0], ez[1] * ez[1], ez[2] * ez[2], ez[3] * ez[3]};
#pragma unroll
  for (int off = 32; off; off >>= 1)
#pragma unroll
    for (int k = 0; k < 8; ++k) q[k] += __shfl_down(q[k], off, 64);
  if ((tid & 63) == 0)
#pragma unroll
    for (int k = 0; k < 8; ++k) wred[wv][k] = q[k];
  __syncthreads();

  unsigned int* cnt = (unsigned int*)(acc + F_CTR);
  float* gcoef = acc + F_COEF;

  // ---- publish: tid0 only; relaxed stores + waitcnt + one relaxed RMW ----
  if (tid == 0) {
#pragma unroll
    for (int k = 0; k < 8; ++k) {
      float s = wred[0][k] + wred[1][k] + wred[2][k] + wred[3][k];
      __hip_atomic_store(&acc[(size_t)blockIdx.x * 8 + k], s, RLX, AGT);
    }
    asm volatile("s_waitcnt vmcnt(0)" ::: "memory");  // stores complete at IC
    unsigned int prev = __hip_atomic_fetch_add(cnt, 1u, RLX, AGT);
    is_last = (prev == (unsigned int)nblk - 1u) ? 1 : 0;
  }
  __syncthreads();

  if (is_last) {
    // last block: reduce all partials (relaxed atomic loads from IC)
    float r[8] = {0.f, 0.f, 0.f, 0.f, 0.f, 0.f, 0.f, 0.f};
    for (int i = tid; i < nblk; i += 256)
#pragma unroll
      for (int k = 0; k < 8; ++k)
        r[k] += __hip_atomic_load(&acc[(size_t)i * 8 + k], RLX, AGT);
#pragma unroll
    for (int off = 32; off; off >>= 1)
#pragma unroll
      for (int k = 0; k < 8; ++k) r[k] += __shfl_down(r[k], off, 64);
    if ((tid & 63) == 0)
#pragma unroll
      for (int k = 0; k < 8; ++k) wred[wv][k] = r[k];
    __syncthreads();
    if (tid == 0) {
      float c0 = bias[0];
#pragma unroll
      for (int w = 0; w < 4; ++w) {
        float Sw = wred[0][w] + wred[1][w] + wred[2][w] + wred[3][w];
        float Qw = wred[0][4 + w] + wred[1][4 + w] + wred[2][4 + w] + wred[3][4 + w];
        float mu = Sw * invB;
        float var = Qw * invB - mu * mu;
        float inv = rsqrtf(var + 1e-5f);
        float cw = W[w] * gamma[w] * inv;
        coefs[w] = cw;
        c0 += W[w] * (beta[w] - gamma[w] * mu * inv);
        __hip_atomic_store(&gcoef[w], cw, RLX, AGT);
      }
      coefs[4] = c0;
      __hip_atomic_store(&gcoef[4], c0, RLX, AGT);
      asm volatile("s_waitcnt vmcnt(0)" ::: "memory");  // coefs complete at IC
#pragma unroll
      for (int f = 0; f < 64; ++f)     // 64 flag copies, own 128B lines
        __hip_atomic_store((unsigned int*)(acc + F_FLAG + f * 32), 1u, RLX, AGT);
    }
  } else {
    // other blocks: poll own flag copy (<=8 pollers/line), then read coefs
    if (tid == 0) {
      unsigned int* myflag =
          (unsigned int*)(acc + F_FLAG + (blockIdx.x & 63) * 32);
      while (__hip_atomic_load(myflag, RLX, AGT) == 0u)
        __builtin_amdgcn_s_sleep(16);
#pragma unroll
      for (int w = 0; w < 5; ++w)
        coefs[w] = __hip_atomic_load(&gcoef[w], RLX, AGT);
    }
  }
  __syncthreads();

  // ---- output ----
  if (valid)
    out[b] = coefs[4] + coefs[0] * ez[0] + coefs[1] * ez[1] +
             coefs[2] * ez[2] + coefs[3] * ez[3];
}

// ================================ launch ====================================
extern "C" void kernel_launch(void* const* d_in, const int* in_sizes, int n_in,
                              void* d_out, int out_size, void* d_ws, size_t ws_size,
                              hipStream_t stream) {
  const float* features    = (const float*)d_in[0];
  const float* rand_params = (const float*)d_in[1];
  const float* rx0         = (const float*)d_in[2];
  const float* ry0         = (const float*)d_in[3];
  const float* rz0         = (const float*)d_in[4];
  const float* crx0        = (const float*)d_in[5];
  const float* gamma       = (const float*)d_in[6];
  const float* beta        = (const float*)d_in[7];
  const float* W           = (const float*)d_in[8];
  const float* bias        = (const float*)d_in[9];
  float* out = (float*)d_out;

  int B = in_sizes[0] / 16;
  int nblk = (B + 255) / 256;   // 512 blocks @ 2/CU: co-resident on 256 CUs

  float* acc = (float*)d_ws;
  // zero counter + coefs + 64 flags region: floats [F_CTR, F_FLAG + 64*32)
  hipMemsetAsync((char*)d_ws + F_CTR * 4, 0,
                 (F_FLAG + 64 * 32 - F_CTR) * 4, stream);

  mono_kernel<<<nblk, 256, 0, stream>>>(
      features, rand_params, rx0, ry0, rz0, crx0, gamma, beta, W, bias,
      acc, out, B, nblk, 1.0f / (float)B);
}

// Round 9
// 25.208 us; speedup vs baseline: 2.3995x; 1.2607x over previous
//
#include <hip/hip_runtime.h>
#include <math.h>

// ---------------------------------------------------------------------------
// FraudDetectionHybrid: 4-qubit statevector sim, algebraically collapsed.
// THREE kernels, no atomics, no memset (dispatch boundary = cheapest barrier):
//   K_A (1 block): constexpr-MT19937(42) gate seq -> U_post via 4-wave-parallel
//       chunks + 2 LDS combine matmuls -> ws.U (built ONCE, not per block)
//   K_B (512 blk): U global->LDS, encoder product state, 16x16 complex matvec
//       (float4 LDS reads), <Z_w> -> ez -> ws + per-block [sum, sumsq] partials
//   K_C (512 blk): redundant partial reduce (L2-cached 16KB) -> BN+Linear
//       coefs -> out[b] = c0 + sum_w a_w ez[b,w]
//
// R1: device MT19937 -> scratch chain (240us). R2: runtime-indexed amp arrays
// -> scratch (100us). R3: runtime-indexed gate args -> scratch (constexpr now).
// R4: dispatch boundaries cost only ~0.5us each. R5: two-kernel = 25.9us.
// R6-R8: grid-barrier mono-kernel: best case ~28us kernel even with relaxed
// IC atomics + distributed flags -> barrier-in-kernel LOSES to dispatch
// boundary. Reverted. R8 lesson applied here: per-block U rebuild cost
// ~2.3us/CU (exec-masked 4-wave chain x 512 blocks) -> build once in K_A.
// ---------------------------------------------------------------------------

// ==================== compile-time numpy RandomState(42) ====================
struct CGates {
  int kind[64];   // 0=RX 1=RY 2=RZ 3=CNOT 4=CRX 5=H 6=SX
  int w0[64];
  int w1[64];
  int pidx[64];   // >=0: rand_params idx; -1 none; -2 rx0; -3 ry0; -4 rz0; -5 crx0
  int ng;
};

constexpr unsigned int c_mt_next(unsigned int (&mt)[624], int& pos) {
  if (pos >= 624) {
    for (int i = 0; i < 624; ++i) {
      unsigned int y = (mt[i] & 0x80000000u) | (mt[(i + 1) % 624] & 0x7fffffffu);
      unsigned int v = mt[(i + 397) % 624] ^ (y >> 1);
      if (y & 1u) v ^= 0x9908b0dfu;
      mt[i] = v;
    }
    pos = 0;
  }
  unsigned int y = mt[pos++];
  y ^= y >> 11;
  y ^= (y << 7) & 0x9d2c5680u;
  y ^= (y << 15) & 0xefc60000u;
  y ^= y >> 18;
  return y;
}

constexpr CGates make_gates() {
  CGates gl{};
  unsigned int mt[624] = {};
  mt[0] = 42u;
  for (int i = 1; i < 624; ++i)
    mt[i] = 1812433253u * (mt[i - 1] ^ (mt[i - 1] >> 30)) + (unsigned int)i;
  int pos = 624;
  int ng = 0, p = 0;
  for (int op = 0; op < 50; ++op) {
    unsigned int k = c_mt_next(mt, pos) & 3u;   // randint(4): one draw, mask 3
    if (k < 3u) {
      unsigned int w = c_mt_next(mt, pos) & 3u; // wire
      gl.kind[ng] = (int)k; gl.w0[ng] = (int)w; gl.w1[ng] = 0;
      gl.pidx[ng] = p++;
      ++ng;
    } else {
      // choice(4,2,replace=False): Fisher-Yates descending, mask-rejection
      int arr[4] = {0, 1, 2, 3};
      { unsigned int j = c_mt_next(mt, pos) & 3u;
        int t = arr[3]; arr[3] = arr[j]; arr[j] = t; }
      { unsigned int j = c_mt_next(mt, pos) & 3u;
        while (j > 2u) j = c_mt_next(mt, pos) & 3u;
        int t = arr[2]; arr[2] = arr[j]; arr[j] = t; }
      { unsigned int j = c_mt_next(mt, pos) & 1u;
        int t = arr[1]; arr[1] = arr[j]; arr[j] = t; }
      gl.kind[ng] = 3; gl.w0[ng] = arr[0]; gl.w1[ng] = arr[1]; gl.pidx[ng] = -1;
      ++ng;
    }
  }
  // trainable block
  gl.kind[ng] = 0; gl.w0[ng] = 0; gl.w1[ng] = 0; gl.pidx[ng] = -2; ++ng; // RX w0
  gl.kind[ng] = 1; gl.w0[ng] = 1; gl.w1[ng] = 0; gl.pidx[ng] = -3; ++ng; // RY w1
  gl.kind[ng] = 2; gl.w0[ng] = 3; gl.w1[ng] = 0; gl.pidx[ng] = -4; ++ng; // RZ w3
  gl.kind[ng] = 4; gl.w0[ng] = 0; gl.w1[ng] = 2; gl.pidx[ng] = -5; ++ng; // CRX(0,2)
  gl.kind[ng] = 5; gl.w0[ng] = 3; gl.w1[ng] = 0; gl.pidx[ng] = -1; ++ng; // H w3
  gl.kind[ng] = 6; gl.w0[ng] = 2; gl.w1[ng] = 0; gl.pidx[ng] = -1; ++ng; // SX w2
  gl.kind[ng] = 3; gl.w0[ng] = 3; gl.w1[ng] = 0; gl.pidx[ng] = -1; ++ng; // CNOT(3,0)
  gl.ng = ng;
  return gl;
}

inline constexpr CGates GL = make_gates();

// chunk boundaries for the 4-wave parallel build
inline constexpr int CK1 = GL.ng / 4;
inline constexpr int CK2 = GL.ng / 2;
inline constexpr int CK3 = (3 * GL.ng) / 4;

// ================= templated gate appliers (static indices) =================
// wire0 = MSB (bit 3): TB = 8 >> wire.

template <int TB>
__device__ __forceinline__ void ap_rx(float (&sx)[16], float (&sy)[16],
                                      float c, float s) {
#pragma unroll
  for (int i = 0; i < 16; ++i) {
    if (i & TB) continue;
    const int j = i | TB;
    float ax = sx[i], ay = sy[i], bx = sx[j], by = sy[j];
    sx[i] = c * ax + s * by;  sy[i] = c * ay - s * bx;   // a' = c a - i s b
    sx[j] = c * bx + s * ay;  sy[j] = c * by - s * ax;   // b' = -i s a + c b
  }
}

template <int TB>
__device__ __forceinline__ void ap_ry(float (&sx)[16], float (&sy)[16],
                                      float c, float s) {
#pragma unroll
  for (int i = 0; i < 16; ++i) {
    if (i & TB) continue;
    const int j = i | TB;
    float ax = sx[i], ay = sy[i], bx = sx[j], by = sy[j];
    sx[i] = c * ax - s * bx;  sy[i] = c * ay - s * by;   // a' = c a - s b
    sx[j] = s * ax + c * bx;  sy[j] = s * ay + c * by;   // b' = s a + c b
  }
}

template <int TB>
__device__ __forceinline__ void ap_rz(float (&sx)[16], float (&sy)[16],
                                      float c, float s) {
#pragma unroll
  for (int i = 0; i < 16; ++i) {
    if (i & TB) continue;
    const int j = i | TB;
    float ax = sx[i], ay = sy[i], bx = sx[j], by = sy[j];
    sx[i] = c * ax + s * ay;  sy[i] = c * ay - s * ax;   // a' = (c - i s) a
    sx[j] = c * bx - s * by;  sy[j] = c * by + s * bx;   // b' = (c + i s) b
  }
}

template <int TB>
__device__ __forceinline__ void ap_h(float (&sx)[16], float (&sy)[16]) {
  const float r = 0.70710678118654752f;
#pragma unroll
  for (int i = 0; i < 16; ++i) {
    if (i & TB) continue;
    const int j = i | TB;
    float ax = sx[i], ay = sy[i], bx = sx[j], by = sy[j];
    sx[i] = r * (ax + bx);  sy[i] = r * (ay + by);
    sx[j] = r * (ax - bx);  sy[j] = r * (ay - by);
  }
}

template <int TB>
__device__ __forceinline__ void ap_sxg(float (&sx)[16], float (&sy)[16]) {
#pragma unroll
  for (int i = 0; i < 16; ++i) {
    if (i & TB) continue;
    const int j = i | TB;
    float ax = sx[i], ay = sy[i], bx = sx[j], by = sy[j];
    // a' = .5((1+i)a + (1-i)b) ; b' = .5((1-i)a + (1+i)b)
    sx[i] = 0.5f * (ax - ay + bx + by);  sy[i] = 0.5f * (ay + ax + by - bx);
    sx[j] = 0.5f * (ax + ay + bx - by);  sy[j] = 0.5f * (ay - ax + by + bx);
  }
}

template <int CB, int TB>
__device__ __forceinline__ void ap_cnot(float (&sx)[16], float (&sy)[16]) {
#pragma unroll
  for (int i = 0; i < 16; ++i) {
    if (!(i & CB) || (i & TB)) continue;
    const int j = i | TB;
    float tx = sx[i], ty = sy[i];
    sx[i] = sx[j]; sy[i] = sy[j];
    sx[j] = tx;    sy[j] = ty;
  }
}

template <int CB, int TB>
__device__ __forceinline__ void ap_crx(float (&sx)[16], float (&sy)[16],
                                       float c, float s) {
#pragma unroll
  for (int i = 0; i < 16; ++i) {
    if (!(i & CB) || (i & TB)) continue;
    const int j = i | TB;
    float ax = sx[i], ay = sy[i], bx = sx[j], by = sy[j];
    sx[i] = c * ax + s * by;  sy[i] = c * ay - s * bx;
    sx[j] = c * bx + s * ay;  sy[j] = c * by - s * ax;
  }
}

// ============== compile-time-unrolled gate chain over [G, GEND) =============
template <int G, int GEND>
__device__ __forceinline__ void apply_range(
    float (&sx)[16], float (&sy)[16], const float* __restrict__ rp,
    const float* __restrict__ rx0, const float* __restrict__ ry0,
    const float* __restrict__ rz0, const float* __restrict__ crx0) {
  if constexpr (G < GEND) {
    constexpr int kind = GL.kind[G];
    constexpr int TB0 = 8 >> GL.w0[G];
    constexpr int TB1 = 8 >> GL.w1[G];
    constexpr int pi = GL.pidx[G];
    float c = 0.f, s = 0.f;
    if constexpr (kind == 0 || kind == 1 || kind == 2 || kind == 4) {
      float th;
      if constexpr (pi >= 0)       th = rp[pi];
      else if constexpr (pi == -2) th = rx0[0];
      else if constexpr (pi == -3) th = ry0[0];
      else if constexpr (pi == -4) th = rz0[0];
      else                         th = crx0[0];
      __sincosf(0.5f * th, &s, &c);
    }
    if constexpr (kind == 0)      ap_rx<TB0>(sx, sy, c, s);
    else if constexpr (kind == 1) ap_ry<TB0>(sx, sy, c, s);
    else if constexpr (kind == 2) ap_rz<TB0>(sx, sy, c, s);
    else if constexpr (kind == 3) ap_cnot<TB0, TB1>(sx, sy);
    else if constexpr (kind == 4) ap_crx<TB0, TB1>(sx, sy, c, s);
    else if constexpr (kind == 5) ap_h<TB0>(sx, sy);
    else                          ap_sxg<TB0>(sx, sy);
    apply_range<G + 1, GEND>(sx, sy, rp, rx0, ry0, rz0, crx0);
  }
}

// ===================== per-element ez, split in two phases ==================
__device__ __forceinline__ void phase1(const float* __restrict__ features,
                                       long long b, float (&t01x)[4],
                                       float (&t01y)[4], float (&t23x)[4],
                                       float (&t23y)[4]) {
  const float4* fp = (const float4*)(features + b * 16);
  float4 F0 = fp[0], F1 = fp[1], F2 = fp[2], F3 = fp[3];
  float L0[4] = {F0.x, F0.y, F0.z, F0.w};
  float L1[4] = {F1.x, F1.y, F1.z, F1.w};
  float L2[4] = {F2.x, F2.y, F2.z, F2.w};
  float L3[4] = {F3.x, F3.y, F3.z, F3.w};
  float vax[4], vay[4], vbx[4], vby[4];
#pragma unroll
  for (int w = 0; w < 4; ++w) {
    // per-wire |0> column of RY(L3) RX(L2) RZ(L1) RY(L0)
    float s0, c0; __sincosf(0.5f * L0[w], &s0, &c0);
    float s1, c1; __sincosf(0.5f * L1[w], &s1, &c1);
    float s2, c2; __sincosf(0.5f * L2[w], &s2, &c2);
    float s3, c3; __sincosf(0.5f * L3[w], &s3, &c3);
    float ax = c0 * c1, ay = -c0 * s1;       // after RZ
    float bx = s0 * c1, by = s0 * s1;
    float a2x = c2 * ax + s2 * by, a2y = c2 * ay - s2 * bx;   // after RX
    float b2x = s2 * ay + c2 * bx, b2y = -s2 * ax + c2 * by;
    vax[w] = c3 * a2x - s3 * b2x; vay[w] = c3 * a2y - s3 * b2y;  // after RY
    vbx[w] = s3 * a2x + c3 * b2x; vby[w] = s3 * a2y + c3 * b2y;
  }
  // pairwise tensor products (wire0 = MSB)
  t01x[0] = vax[0] * vax[1] - vay[0] * vay[1]; t01y[0] = vax[0] * vay[1] + vay[0] * vax[1];
  t01x[1] = vax[0] * vbx[1] - vay[0] * vby[1]; t01y[1] = vax[0] * vby[1] + vay[0] * vbx[1];
  t01x[2] = vbx[0] * vax[1] - vby[0] * vay[1]; t01y[2] = vbx[0] * vay[1] + vby[0] * vax[1];
  t01x[3] = vbx[0] * vbx[1] - vby[0] * vby[1]; t01y[3] = vbx[0] * vby[1] + vby[0] * vbx[1];
  t23x[0] = vax[2] * vax[3] - vay[2] * vay[3]; t23y[0] = vax[2] * vay[3] + vay[2] * vax[3];
  t23x[1] = vax[2] * vbx[3] - vay[2] * vby[3]; t23y[1] = vax[2] * vby[3] + vay[2] * vbx[3];
  t23x[2] = vbx[2] * vax[3] - vby[2] * vay[3]; t23y[2] = vbx[2] * vay[3] + vby[2] * vax[3];
  t23x[3] = vbx[2] * vbx[3] - vby[2] * vby[3]; t23y[3] = vbx[2] * vby[3] + vby[2] * vbx[3];
}

// phase 2 with float4 LDS reads (2 complex per ds_read_b128)
__device__ __forceinline__ void phase2(const float4* __restrict__ U4,
                                       const float (&t01x)[4], const float (&t01y)[4],
                                       const float (&t23x)[4], const float (&t23y)[4],
                                       float (&ez)[4]) {
  float sx[16], sy[16];
#pragma unroll
  for (int i = 0; i < 16; ++i) {
    int a = i >> 2, c = i & 3;
    sx[i] = t01x[a] * t23x[c] - t01y[a] * t23y[c];
    sy[i] = t01x[a] * t23y[c] + t01y[a] * t23x[c];
  }
  float e0 = 0.f, e1 = 0.f, e2 = 0.f, e3 = 0.f;
#pragma unroll
  for (int i = 0; i < 16; ++i) {
    float ax = 0.f, ay = 0.f;
#pragma unroll
    for (int j2 = 0; j2 < 8; ++j2) {
      float4 u = U4[i * 8 + j2];          // (re0, im0, re1, im1)
      int j = 2 * j2;
      ax += u.x * sx[j] - u.y * sy[j] + u.z * sx[j + 1] - u.w * sy[j + 1];
      ay += u.x * sy[j] + u.y * sx[j] + u.z * sy[j + 1] + u.w * sx[j + 1];
    }
    float p = ax * ax + ay * ay;
    e0 += (i & 8) ? -p : p;
    e1 += (i & 4) ? -p : p;
    e2 += (i & 2) ? -p : p;
    e3 += (i & 1) ? -p : p;
  }
  ez[0] = e0; ez[1] = e1; ez[2] = e2; ez[3] = e3;
}

// =================== K_A: build U once (1 block, 4 waves) ===================
__global__ __launch_bounds__(256) void build_u_kernel(
    const float* __restrict__ rand_params, const float* __restrict__ rx0,
    const float* __restrict__ ry0, const float* __restrict__ rz0,
    const float* __restrict__ crx0, float2* __restrict__ U_out) {
  __shared__ float2 chunks[4][256];
  __shared__ float2 comb[2][256];
  int tid = threadIdx.x;
  int wv = tid >> 6, lane = tid & 63;

  if (lane < 16) {
    float sx[16], sy[16];
#pragma unroll
    for (int i = 0; i < 16; ++i) { sx[i] = (i == lane) ? 1.f : 0.f; sy[i] = 0.f; }
    if (wv == 0)      apply_range<0,   CK1  >(sx, sy, rand_params, rx0, ry0, rz0, crx0);
    else if (wv == 1) apply_range<CK1, CK2  >(sx, sy, rand_params, rx0, ry0, rz0, crx0);
    else if (wv == 2) apply_range<CK2, CK3  >(sx, sy, rand_params, rx0, ry0, rz0, crx0);
    else              apply_range<CK3, GL.ng>(sx, sy, rand_params, rx0, ry0, rz0, crx0);
#pragma unroll
    for (int i = 0; i < 16; ++i)
      chunks[wv][i * 16 + lane] = make_float2(sx[i], sy[i]);
  }
  __syncthreads();

  // combine round 1: C10 = G1*G0, C32 = G3*G2 (one element/thread)
  {
    int r = tid >> 4, c = tid & 15;
    float xr = 0.f, xi = 0.f, yr = 0.f, yi = 0.f;
#pragma unroll
    for (int k = 0; k < 16; ++k) {
      float2 g1 = chunks[1][r * 16 + k], g0 = chunks[0][k * 16 + c];
      xr += g1.x * g0.x - g1.y * g0.y;  xi += g1.x * g0.y + g1.y * g0.x;
      float2 g3 = chunks[3][r * 16 + k], g2 = chunks[2][k * 16 + c];
      yr += g3.x * g2.x - g3.y * g2.y;  yi += g3.x * g2.y + g3.y * g2.x;
    }
    comb[0][r * 16 + c] = make_float2(xr, xi);
    comb[1][r * 16 + c] = make_float2(yr, yi);
  }
  __syncthreads();

  // combine round 2: U = C32*C10, write to global
  {
    int r = tid >> 4, c = tid & 15;
    float ur = 0.f, ui = 0.f;
#pragma unroll
    for (int k = 0; k < 16; ++k) {
      float2 a = comb[1][r * 16 + k], d = comb[0][k * 16 + c];
      ur += a.x * d.x - a.y * d.y;
      ui += a.x * d.y + a.y * d.x;
    }
    U_out[r * 16 + c] = make_float2(ur, ui);
  }
}

// ============== K_B: encoder + matvec + ez + block partials =================
__global__ __launch_bounds__(256) void main_kernel(
    const float* __restrict__ features, const float2* __restrict__ U,
    float* __restrict__ ez_out, float* __restrict__ partials, int B, int useEz) {
  __shared__ float2 ldsU[256];
  __shared__ float wred[4][8];
  int tid = threadIdx.x;
  ldsU[tid] = U[tid];

  long long b = (long long)blockIdx.x * 256 + tid;
  bool valid = b < B;
  float t01x[4], t01y[4], t23x[4], t23y[4];
  if (valid) phase1(features, b, t01x, t01y, t23x, t23y);
  __syncthreads();

  float ez[4] = {0.f, 0.f, 0.f, 0.f};
  if (valid) {
    phase2((const float4*)ldsU, t01x, t01y, t23x, t23y, ez);
    if (useEz) ((float4*)ez_out)[b] = make_float4(ez[0], ez[1], ez[2], ez[3]);
  }
  float q[8] = {ez[0], ez[1], ez[2], ez[3],
                ez[0] * ez[0], ez[1] * ez[1], ez[2] * ez[2], ez[3] * ez[3]};
#pragma unroll
  for (int off = 32; off; off >>= 1)
#pragma unroll
    for (int k = 0; k < 8; ++k) q[k] += __shfl_down(q[k], off, 64);
  int lane = tid & 63, wv = tid >> 6;
  if (lane == 0)
#pragma unroll
    for (int k = 0; k < 8; ++k) wred[wv][k] = q[k];
  __syncthreads();
  if (tid == 0) {
#pragma unroll
    for (int k = 0; k < 8; ++k)
      partials[(size_t)blockIdx.x * 8 + k] =
          wred[0][k] + wred[1][k] + wred[2][k] + wred[3][k];
  }
}

// ========= K_C: redundant stats reduce -> coefs -> output pass ==============
__global__ __launch_bounds__(256) void out_kernel(
    const float* __restrict__ partials, int nblk,
    const float* __restrict__ gamma, const float* __restrict__ beta,
    const float* __restrict__ W, const float* __restrict__ bias,
    const float* __restrict__ ez_in, const float* __restrict__ features,
    const float2* __restrict__ U, float* __restrict__ out,
    int B, int useEz, float invB) {
  __shared__ float wred[4][8];
  __shared__ float coefs[5];
  __shared__ float2 ldsU[256];
  int tid = threadIdx.x;

  float q[8] = {0.f, 0.f, 0.f, 0.f, 0.f, 0.f, 0.f, 0.f};
  for (int idx = tid; idx < nblk; idx += 256) {
    const float4* p4 = (const float4*)(partials + (size_t)idx * 8);
    float4 A = p4[0], Bq = p4[1];
    q[0] += A.x;  q[1] += A.y;  q[2] += A.z;  q[3] += A.w;
    q[4] += Bq.x; q[5] += Bq.y; q[6] += Bq.z; q[7] += Bq.w;
  }
#pragma unroll
  for (int off = 32; off; off >>= 1)
#pragma unroll
    for (int k = 0; k < 8; ++k) q[k] += __shfl_down(q[k], off, 64);
  int lane = tid & 63, wv = tid >> 6;
  if (lane == 0)
#pragma unroll
    for (int k = 0; k < 8; ++k) wred[wv][k] = q[k];
  if (!useEz) ldsU[tid] = U[tid];
  __syncthreads();
  if (tid == 0) {
    float c0 = bias[0];
#pragma unroll
    for (int w = 0; w < 4; ++w) {
      float Sw = wred[0][w] + wred[1][w] + wred[2][w] + wred[3][w];
      float Qw = wred[0][4 + w] + wred[1][4 + w] + wred[2][4 + w] + wred[3][4 + w];
      float mu = Sw * invB;
      float var = Qw * invB - mu * mu;
      float inv = rsqrtf(var + 1e-5f);
      coefs[w] = W[w] * gamma[w] * inv;
      c0 += W[w] * (beta[w] - gamma[w] * mu * inv);
    }
    coefs[4] = c0;
  }
  __syncthreads();

  long long b = (long long)blockIdx.x * 256 + tid;
  if (b >= B) return;
  float ez[4];
  if (useEz) {
    float4 e = ((const float4*)ez_in)[b];
    ez[0] = e.x; ez[1] = e.y; ez[2] = e.z; ez[3] = e.w;
  } else {
    float t01x[4], t01y[4], t23x[4], t23y[4];
    phase1(features, b, t01x, t01y, t23x, t23y);
    phase2((const float4*)ldsU, t01x, t01y, t23x, t23y, ez);
  }
  out[b] = coefs[4] + coefs[0] * ez[0] + coefs[1] * ez[1] +
           coefs[2] * ez[2] + coefs[3] * ez[3];
}

// ================================ launch ====================================
extern "C" void kernel_launch(void* const* d_in, const int* in_sizes, int n_in,
                              void* d_out, int out_size, void* d_ws, size_t ws_size,
                              hipStream_t stream) {
  const float* features    = (const float*)d_in[0];
  const float* rand_params = (const float*)d_in[1];
  const float* rx0         = (const float*)d_in[2];
  const float* ry0         = (const float*)d_in[3];
  const float* rz0         = (const float*)d_in[4];
  const float* crx0        = (const float*)d_in[5];
  const float* gamma       = (const float*)d_in[6];
  const float* beta        = (const float*)d_in[7];
  const float* W           = (const float*)d_in[8];
  const float* bias        = (const float*)d_in[9];
  float* out = (float*)d_out;

  int B = in_sizes[0] / 16;
  int nblk = (B + 255) / 256;

  char* ws = (char*)d_ws;
  float2* U = (float2*)ws;                                   // 2048 B
  float* partials = (float*)(ws + 2048);                     // nblk*32 B
  size_t ez_off = (2048 + (size_t)nblk * 32 + 255) & ~(size_t)255;
  float* ez = (float*)(ws + ez_off);
  int useEz = (ws_size >= ez_off + (size_t)B * 16) ? 1 : 0;

  build_u_kernel<<<1, 256, 0, stream>>>(rand_params, rx0, ry0, rz0, crx0, U);
  main_kernel<<<nblk, 256, 0, stream>>>(features, U, ez, partials, B, useEz);
  out_kernel<<<nblk, 256, 0, stream>>>(partials, nblk, gamma, beta, W, bias,
                                       ez, features, U, out, B, useEz,
                                       1.0f / (float)B);
}

// Round 10
// 24.178 us; speedup vs baseline: 2.5017x; 1.0426x over previous
//
#include <hip/hip_runtime.h>
#include <math.h>

// ---------------------------------------------------------------------------
// FraudDetectionHybrid: 4-qubit statevector sim, algebraically collapsed.
// THREE kernels, no atomics, no memset (dispatch boundary = cheapest barrier):
//   K_A (1 block): constexpr-MT19937(42) gate seq -> U_post via 4-wave-parallel
//       chunks + 2 LDS combine matmuls -> ws.U (built ONCE)
//   K_B (512 blk): encoder product state, 16x16 complex matvec reading U
//       DIRECTLY FROM GLOBAL with wave-uniform unrolled offsets (-> s_load
//       from scalar K$; zero LDS/VALU issue cost), <Z_w> -> ez + partials
//   K_C (512 blk): redundant partial reduce -> BN+Linear coefs -> out
//
// R1: device MT19937 -> scratch chain (240us). R2: runtime-indexed amp arrays
// -> scratch (100us). R3: runtime-indexed gate args -> scratch. R4: dispatch
// boundaries ~0.5us. R5-R8: in-kernel grid barriers all lose to dispatch
// boundaries. R9: calibration says K_B alone ~17us vs ~2.5us instruction
// model -> suspect (a) __sincosf not inlining (OCML call + spills), and
// (b) 128 uniform ds_read_b128/thread on a shared LDS pipe. This round:
// __sinf/__cosf natives + global-uniform U reads (s_load path). 
// ---------------------------------------------------------------------------

// ==================== compile-time numpy RandomState(42) ====================
struct CGates {
  int kind[64];   // 0=RX 1=RY 2=RZ 3=CNOT 4=CRX 5=H 6=SX
  int w0[64];
  int w1[64];
  int pidx[64];   // >=0: rand_params idx; -1 none; -2 rx0; -3 ry0; -4 rz0; -5 crx0
  int ng;
};

constexpr unsigned int c_mt_next(unsigned int (&mt)[624], int& pos) {
  if (pos >= 624) {
    for (int i = 0; i < 624; ++i) {
      unsigned int y = (mt[i] & 0x80000000u) | (mt[(i + 1) % 624] & 0x7fffffffu);
      unsigned int v = mt[(i + 397) % 624] ^ (y >> 1);
      if (y & 1u) v ^= 0x9908b0dfu;
      mt[i] = v;
    }
    pos = 0;
  }
  unsigned int y = mt[pos++];
  y ^= y >> 11;
  y ^= (y << 7) & 0x9d2c5680u;
  y ^= (y << 15) & 0xefc60000u;
  y ^= y >> 18;
  return y;
}

constexpr CGates make_gates() {
  CGates gl{};
  unsigned int mt[624] = {};
  mt[0] = 42u;
  for (int i = 1; i < 624; ++i)
    mt[i] = 1812433253u * (mt[i - 1] ^ (mt[i - 1] >> 30)) + (unsigned int)i;
  int pos = 624;
  int ng = 0, p = 0;
  for (int op = 0; op < 50; ++op) {
    unsigned int k = c_mt_next(mt, pos) & 3u;   // randint(4): one draw, mask 3
    if (k < 3u) {
      unsigned int w = c_mt_next(mt, pos) & 3u; // wire
      gl.kind[ng] = (int)k; gl.w0[ng] = (int)w; gl.w1[ng] = 0;
      gl.pidx[ng] = p++;
      ++ng;
    } else {
      // choice(4,2,replace=False): Fisher-Yates descending, mask-rejection
      int arr[4] = {0, 1, 2, 3};
      { unsigned int j = c_mt_next(mt, pos) & 3u;
        int t = arr[3]; arr[3] = arr[j]; arr[j] = t; }
      { unsigned int j = c_mt_next(mt, pos) & 3u;
        while (j > 2u) j = c_mt_next(mt, pos) & 3u;
        int t = arr[2]; arr[2] = arr[j]; arr[j] = t; }
      { unsigned int j = c_mt_next(mt, pos) & 1u;
        int t = arr[1]; arr[1] = arr[j]; arr[j] = t; }
      gl.kind[ng] = 3; gl.w0[ng] = arr[0]; gl.w1[ng] = arr[1]; gl.pidx[ng] = -1;
      ++ng;
    }
  }
  // trainable block
  gl.kind[ng] = 0; gl.w0[ng] = 0; gl.w1[ng] = 0; gl.pidx[ng] = -2; ++ng; // RX w0
  gl.kind[ng] = 1; gl.w0[ng] = 1; gl.w1[ng] = 0; gl.pidx[ng] = -3; ++ng; // RY w1
  gl.kind[ng] = 2; gl.w0[ng] = 3; gl.w1[ng] = 0; gl.pidx[ng] = -4; ++ng; // RZ w3
  gl.kind[ng] = 4; gl.w0[ng] = 0; gl.w1[ng] = 2; gl.pidx[ng] = -5; ++ng; // CRX(0,2)
  gl.kind[ng] = 5; gl.w0[ng] = 3; gl.w1[ng] = 0; gl.pidx[ng] = -1; ++ng; // H w3
  gl.kind[ng] = 6; gl.w0[ng] = 2; gl.w1[ng] = 0; gl.pidx[ng] = -1; ++ng; // SX w2
  gl.kind[ng] = 3; gl.w0[ng] = 3; gl.w1[ng] = 0; gl.pidx[ng] = -1; ++ng; // CNOT(3,0)
  gl.ng = ng;
  return gl;
}

inline constexpr CGates GL = make_gates();

// chunk boundaries for the 4-wave parallel build
inline constexpr int CK1 = GL.ng / 4;
inline constexpr int CK2 = GL.ng / 2;
inline constexpr int CK3 = (3 * GL.ng) / 4;

// ================= templated gate appliers (static indices) =================
// wire0 = MSB (bit 3): TB = 8 >> wire.

template <int TB>
__device__ __forceinline__ void ap_rx(float (&sx)[16], float (&sy)[16],
                                      float c, float s) {
#pragma unroll
  for (int i = 0; i < 16; ++i) {
    if (i & TB) continue;
    const int j = i | TB;
    float ax = sx[i], ay = sy[i], bx = sx[j], by = sy[j];
    sx[i] = c * ax + s * by;  sy[i] = c * ay - s * bx;   // a' = c a - i s b
    sx[j] = c * bx + s * ay;  sy[j] = c * by - s * ax;   // b' = -i s a + c b
  }
}

template <int TB>
__device__ __forceinline__ void ap_ry(float (&sx)[16], float (&sy)[16],
                                      float c, float s) {
#pragma unroll
  for (int i = 0; i < 16; ++i) {
    if (i & TB) continue;
    const int j = i | TB;
    float ax = sx[i], ay = sy[i], bx = sx[j], by = sy[j];
    sx[i] = c * ax - s * bx;  sy[i] = c * ay - s * by;   // a' = c a - s b
    sx[j] = s * ax + c * bx;  sy[j] = s * ay + c * by;   // b' = s a + c b
  }
}

template <int TB>
__device__ __forceinline__ void ap_rz(float (&sx)[16], float (&sy)[16],
                                      float c, float s) {
#pragma unroll
  for (int i = 0; i < 16; ++i) {
    if (i & TB) continue;
    const int j = i | TB;
    float ax = sx[i], ay = sy[i], bx = sx[j], by = sy[j];
    sx[i] = c * ax + s * ay;  sy[i] = c * ay - s * ax;   // a' = (c - i s) a
    sx[j] = c * bx - s * by;  sy[j] = c * by + s * bx;   // b' = (c + i s) b
  }
}

template <int TB>
__device__ __forceinline__ void ap_h(float (&sx)[16], float (&sy)[16]) {
  const float r = 0.70710678118654752f;
#pragma unroll
  for (int i = 0; i < 16; ++i) {
    if (i & TB) continue;
    const int j = i | TB;
    float ax = sx[i], ay = sy[i], bx = sx[j], by = sy[j];
    sx[i] = r * (ax + bx);  sy[i] = r * (ay + by);
    sx[j] = r * (ax - bx);  sy[j] = r * (ay - by);
  }
}

template <int TB>
__device__ __forceinline__ void ap_sxg(float (&sx)[16], float (&sy)[16]) {
#pragma unroll
  for (int i = 0; i < 16; ++i) {
    if (i & TB) continue;
    const int j = i | TB;
    float ax = sx[i], ay = sy[i], bx = sx[j], by = sy[j];
    // a' = .5((1+i)a + (1-i)b) ; b' = .5((1-i)a + (1+i)b)
    sx[i] = 0.5f * (ax - ay + bx + by);  sy[i] = 0.5f * (ay + ax + by - bx);
    sx[j] = 0.5f * (ax + ay + bx - by);  sy[j] = 0.5f * (ay - ax + by + bx);
  }
}

template <int CB, int TB>
__device__ __forceinline__ void ap_cnot(float (&sx)[16], float (&sy)[16]) {
#pragma unroll
  for (int i = 0; i < 16; ++i) {
    if (!(i & CB) || (i & TB)) continue;
    const int j = i | TB;
    float tx = sx[i], ty = sy[i];
    sx[i] = sx[j]; sy[i] = sy[j];
    sx[j] = tx;    sy[j] = ty;
  }
}

template <int CB, int TB>
__device__ __forceinline__ void ap_crx(float (&sx)[16], float (&sy)[16],
                                       float c, float s) {
#pragma unroll
  for (int i = 0; i < 16; ++i) {
    if (!(i & CB) || (i & TB)) continue;
    const int j = i | TB;
    float ax = sx[i], ay = sy[i], bx = sx[j], by = sy[j];
    sx[i] = c * ax + s * by;  sy[i] = c * ay - s * bx;
    sx[j] = c * bx + s * ay;  sy[j] = c * by - s * ax;
  }
}

// ============== compile-time-unrolled gate chain over [G, GEND) =============
template <int G, int GEND>
__device__ __forceinline__ void apply_range(
    float (&sx)[16], float (&sy)[16], const float* __restrict__ rp,
    const float* __restrict__ rx0, const float* __restrict__ ry0,
    const float* __restrict__ rz0, const float* __restrict__ crx0) {
  if constexpr (G < GEND) {
    constexpr int kind = GL.kind[G];
    constexpr int TB0 = 8 >> GL.w0[G];
    constexpr int TB1 = 8 >> GL.w1[G];
    constexpr int pi = GL.pidx[G];
    float c = 0.f, s = 0.f;
    if constexpr (kind == 0 || kind == 1 || kind == 2 || kind == 4) {
      float th;
      if constexpr (pi >= 0)       th = rp[pi];
      else if constexpr (pi == -2) th = rx0[0];
      else if constexpr (pi == -3) th = ry0[0];
      else if constexpr (pi == -4) th = rz0[0];
      else                         th = crx0[0];
      float h = 0.5f * th;
      s = __sinf(h);
      c = __cosf(h);
    }
    if constexpr (kind == 0)      ap_rx<TB0>(sx, sy, c, s);
    else if constexpr (kind == 1) ap_ry<TB0>(sx, sy, c, s);
    else if constexpr (kind == 2) ap_rz<TB0>(sx, sy, c, s);
    else if constexpr (kind == 3) ap_cnot<TB0, TB1>(sx, sy);
    else if constexpr (kind == 4) ap_crx<TB0, TB1>(sx, sy, c, s);
    else if constexpr (kind == 5) ap_h<TB0>(sx, sy);
    else                          ap_sxg<TB0>(sx, sy);
    apply_range<G + 1, GEND>(sx, sy, rp, rx0, ry0, rz0, crx0);
  }
}

// ===================== per-element ez, split in two phases ==================
__device__ __forceinline__ void phase1(const float* __restrict__ features,
                                       long long b, float (&t01x)[4],
                                       float (&t01y)[4], float (&t23x)[4],
                                       float (&t23y)[4]) {
  const float4* fp = (const float4*)(features + b * 16);
  float4 F0 = fp[0], F1 = fp[1], F2 = fp[2], F3 = fp[3];
  float L0[4] = {F0.x, F0.y, F0.z, F0.w};
  float L1[4] = {F1.x, F1.y, F1.z, F1.w};
  float L2[4] = {F2.x, F2.y, F2.z, F2.w};
  float L3[4] = {F3.x, F3.y, F3.z, F3.w};
  float vax[4], vay[4], vbx[4], vby[4];
#pragma unroll
  for (int w = 0; w < 4; ++w) {
    // per-wire |0> column of RY(L3) RX(L2) RZ(L1) RY(L0)
    float h0 = 0.5f * L0[w], h1 = 0.5f * L1[w];
    float h2 = 0.5f * L2[w], h3 = 0.5f * L3[w];
    float s0 = __sinf(h0), c0 = __cosf(h0);
    float s1 = __sinf(h1), c1 = __cosf(h1);
    float s2 = __sinf(h2), c2 = __cosf(h2);
    float s3 = __sinf(h3), c3 = __cosf(h3);
    float ax = c0 * c1, ay = -c0 * s1;       // after RZ
    float bx = s0 * c1, by = s0 * s1;
    float a2x = c2 * ax + s2 * by, a2y = c2 * ay - s2 * bx;   // after RX
    float b2x = s2 * ay + c2 * bx, b2y = -s2 * ax + c2 * by;
    vax[w] = c3 * a2x - s3 * b2x; vay[w] = c3 * a2y - s3 * b2y;  // after RY
    vbx[w] = s3 * a2x + c3 * b2x; vby[w] = s3 * a2y + c3 * b2y;
  }
  // pairwise tensor products (wire0 = MSB)
  t01x[0] = vax[0] * vax[1] - vay[0] * vay[1]; t01y[0] = vax[0] * vay[1] + vay[0] * vax[1];
  t01x[1] = vax[0] * vbx[1] - vay[0] * vby[1]; t01y[1] = vax[0] * vby[1] + vay[0] * vbx[1];
  t01x[2] = vbx[0] * vax[1] - vby[0] * vay[1]; t01y[2] = vbx[0] * vay[1] + vby[0] * vax[1];
  t01x[3] = vbx[0] * vbx[1] - vby[0] * vby[1]; t01y[3] = vbx[0] * vby[1] + vby[0] * vbx[1];
  t23x[0] = vax[2] * vax[3] - vay[2] * vay[3]; t23y[0] = vax[2] * vay[3] + vay[2] * vax[3];
  t23x[1] = vax[2] * vbx[3] - vay[2] * vby[3]; t23y[1] = vax[2] * vby[3] + vay[2] * vbx[3];
  t23x[2] = vbx[2] * vax[3] - vby[2] * vay[3]; t23y[2] = vbx[2] * vay[3] + vby[2] * vax[3];
  t23x[3] = vbx[2] * vbx[3] - vby[2] * vby[3]; t23y[3] = vbx[2] * vby[3] + vby[2] * vbx[3];
}

// phase 2: matvec reading U from GLOBAL with wave-uniform unrolled offsets.
// U4 is const __restrict__ and never written by this kernel -> LLVM's
// uniform-load pass should emit s_load (scalar K$), costing no VALU issue.
__device__ __forceinline__ void phase2(const float4* __restrict__ U4,
                                       const float (&t01x)[4], const float (&t01y)[4],
                                       const float (&t23x)[4], const float (&t23y)[4],
                                       float (&ez)[4]) {
  float sx[16], sy[16];
#pragma unroll
  for (int i = 0; i < 16; ++i) {
    int a = i >> 2, c = i & 3;
    sx[i] = t01x[a] * t23x[c] - t01y[a] * t23y[c];
    sy[i] = t01x[a] * t23y[c] + t01y[a] * t23x[c];
  }
  float e0 = 0.f, e1 = 0.f, e2 = 0.f, e3 = 0.f;
#pragma unroll
  for (int i = 0; i < 16; ++i) {
    float ax = 0.f, ay = 0.f;
#pragma unroll
    for (int j2 = 0; j2 < 8; ++j2) {
      float4 u = U4[i * 8 + j2];          // (re0, im0, re1, im1), uniform addr
      int j = 2 * j2;
      ax += u.x * sx[j] - u.y * sy[j] + u.z * sx[j + 1] - u.w * sy[j + 1];
      ay += u.x * sy[j] + u.y * sx[j] + u.z * sy[j + 1] + u.w * sx[j + 1];
    }
    float p = ax * ax + ay * ay;
    e0 += (i & 8) ? -p : p;
    e1 += (i & 4) ? -p : p;
    e2 += (i & 2) ? -p : p;
    e3 += (i & 1) ? -p : p;
  }
  ez[0] = e0; ez[1] = e1; ez[2] = e2; ez[3] = e3;
}

// =================== K_A: build U once (1 block, 4 waves) ===================
__global__ __launch_bounds__(256) void build_u_kernel(
    const float* __restrict__ rand_params, const float* __restrict__ rx0,
    const float* __restrict__ ry0, const float* __restrict__ rz0,
    const float* __restrict__ crx0, float2* __restrict__ U_out) {
  __shared__ float2 chunks[4][256];
  __shared__ float2 comb[2][256];
  int tid = threadIdx.x;
  int wv = tid >> 6, lane = tid & 63;

  if (lane < 16) {
    float sx[16], sy[16];
#pragma unroll
    for (int i = 0; i < 16; ++i) { sx[i] = (i == lane) ? 1.f : 0.f; sy[i] = 0.f; }
    if (wv == 0)      apply_range<0,   CK1  >(sx, sy, rand_params, rx0, ry0, rz0, crx0);
    else if (wv == 1) apply_range<CK1, CK2  >(sx, sy, rand_params, rx0, ry0, rz0, crx0);
    else if (wv == 2) apply_range<CK2, CK3  >(sx, sy, rand_params, rx0, ry0, rz0, crx0);
    else              apply_range<CK3, GL.ng>(sx, sy, rand_params, rx0, ry0, rz0, crx0);
#pragma unroll
    for (int i = 0; i < 16; ++i)
      chunks[wv][i * 16 + lane] = make_float2(sx[i], sy[i]);
  }
  __syncthreads();

  // combine round 1: C10 = G1*G0, C32 = G3*G2 (one element/thread)
  {
    int r = tid >> 4, c = tid & 15;
    float xr = 0.f, xi = 0.f, yr = 0.f, yi = 0.f;
#pragma unroll
    for (int k = 0; k < 16; ++k) {
      float2 g1 = chunks[1][r * 16 + k], g0 = chunks[0][k * 16 + c];
      xr += g1.x * g0.x - g1.y * g0.y;  xi += g1.x * g0.y + g1.y * g0.x;
      float2 g3 = chunks[3][r * 16 + k], g2 = chunks[2][k * 16 + c];
      yr += g3.x * g2.x - g3.y * g2.y;  yi += g3.x * g2.y + g3.y * g2.x;
    }
    comb[0][r * 16 + c] = make_float2(xr, xi);
    comb[1][r * 16 + c] = make_float2(yr, yi);
  }
  __syncthreads();

  // combine round 2: U = C32*C10, write to global
  {
    int r = tid >> 4, c = tid & 15;
    float ur = 0.f, ui = 0.f;
#pragma unroll
    for (int k = 0; k < 16; ++k) {
      float2 a = comb[1][r * 16 + k], d = comb[0][k * 16 + c];
      ur += a.x * d.x - a.y * d.y;
      ui += a.x * d.y + a.y * d.x;
    }
    U_out[r * 16 + c] = make_float2(ur, ui);
  }
}

// ============== K_B: encoder + matvec + ez + block partials =================
__global__ __launch_bounds__(256) void main_kernel(
    const float* __restrict__ features, const float4* __restrict__ U4,
    float* __restrict__ ez_out, float* __restrict__ partials, int B, int useEz) {
  __shared__ float wred[4][8];
  int tid = threadIdx.x;

  long long b = (long long)blockIdx.x * 256 + tid;
  bool valid = b < B;
  float t01x[4], t01y[4], t23x[4], t23y[4];
  if (valid) phase1(features, b, t01x, t01y, t23x, t23y);

  float ez[4] = {0.f, 0.f, 0.f, 0.f};
  if (valid) {
    phase2(U4, t01x, t01y, t23x, t23y, ez);
    if (useEz) ((float4*)ez_out)[b] = make_float4(ez[0], ez[1], ez[2], ez[3]);
  }
  float q[8] = {ez[0], ez[1], ez[2], ez[3],
                ez[0] * ez[0], ez[1] * ez[1], ez[2] * ez[2], ez[3] * ez[3]};
#pragma unroll
  for (int off = 32; off; off >>= 1)
#pragma unroll
    for (int k = 0; k < 8; ++k) q[k] += __shfl_down(q[k], off, 64);
  int lane = tid & 63, wv = tid >> 6;
  if (lane == 0)
#pragma unroll
    for (int k = 0; k < 8; ++k) wred[wv][k] = q[k];
  __syncthreads();
  if (tid == 0) {
#pragma unroll
    for (int k = 0; k < 8; ++k)
      partials[(size_t)blockIdx.x * 8 + k] =
          wred[0][k] + wred[1][k] + wred[2][k] + wred[3][k];
  }
}

// ========= K_C: redundant stats reduce -> coefs -> output pass ==============
__global__ __launch_bounds__(256) void out_kernel(
    const float* __restrict__ partials, int nblk,
    const float* __restrict__ gamma, const float* __restrict__ beta,
    const float* __restrict__ W, const float* __restrict__ bias,
    const float* __restrict__ ez_in, const float* __restrict__ features,
    const float4* __restrict__ U4, float* __restrict__ out,
    int B, int useEz, float invB) {
  __shared__ float wred[4][8];
  __shared__ float coefs[5];
  int tid = threadIdx.x;

  float q[8] = {0.f, 0.f, 0.f, 0.f, 0.f, 0.f, 0.f, 0.f};
  for (int idx = tid; idx < nblk; idx += 256) {
    const float4* p4 = (const float4*)(partials + (size_t)idx * 8);
    float4 A = p4[0], Bq = p4[1];
    q[0] += A.x;  q[1] += A.y;  q[2] += A.z;  q[3] += A.w;
    q[4] += Bq.x; q[5] += Bq.y; q[6] += Bq.z; q[7] += Bq.w;
  }
#pragma unroll
  for (int off = 32; off; off >>= 1)
#pragma unroll
    for (int k = 0; k < 8; ++k) q[k] += __shfl_down(q[k], off, 64);
  int lane = tid & 63, wv = tid >> 6;
  if (lane == 0)
#pragma unroll
    for (int k = 0; k < 8; ++k) wred[wv][k] = q[k];
  __syncthreads();
  if (tid == 0) {
    float c0 = bias[0];
#pragma unroll
    for (int w = 0; w < 4; ++w) {
      float Sw = wred[0][w] + wred[1][w] + wred[2][w] + wred[3][w];
      float Qw = wred[0][4 + w] + wred[1][4 + w] + wred[2][4 + w] + wred[3][4 + w];
      float mu = Sw * invB;
      float var = Qw * invB - mu * mu;
      float inv = rsqrtf(var + 1e-5f);
      coefs[w] = W[w] * gamma[w] * inv;
      c0 += W[w] * (beta[w] - gamma[w] * mu * inv);
    }
    coefs[4] = c0;
  }
  __syncthreads();

  long long b = (long long)blockIdx.x * 256 + tid;
  if (b >= B) return;
  float ez[4];
  if (useEz) {
    float4 e = ((const float4*)ez_in)[b];
    ez[0] = e.x; ez[1] = e.y; ez[2] = e.z; ez[3] = e.w;
  } else {
    float t01x[4], t01y[4], t23x[4], t23y[4];
    phase1(features, b, t01x, t01y, t23x, t23y);
    phase2(U4, t01x, t01y, t23x, t23y, ez);
  }
  out[b] = coefs[4] + coefs[0] * ez[0] + coefs[1] * ez[1] +
           coefs[2] * ez[2] + coefs[3] * ez[3];
}

// ================================ launch ====================================
extern "C" void kernel_launch(void* const* d_in, const int* in_sizes, int n_in,
                              void* d_out, int out_size, void* d_ws, size_t ws_size,
                              hipStream_t stream) {
  const float* features    = (const float*)d_in[0];
  const float* rand_params = (const float*)d_in[1];
  const float* rx0         = (const float*)d_in[2];
  const float* ry0         = (const float*)d_in[3];
  const float* rz0         = (const float*)d_in[4];
  const float* crx0        = (const float*)d_in[5];
  const float* gamma       = (const float*)d_in[6];
  const float* beta        = (const float*)d_in[7];
  const float* W           = (const float*)d_in[8];
  const float* bias        = (const float*)d_in[9];
  float* out = (float*)d_out;

  int B = in_sizes[0] / 16;
  int nblk = (B + 255) / 256;

  char* ws = (char*)d_ws;
  float2* U = (float2*)ws;                                   // 2048 B
  float* partials = (float*)(ws + 2048);                     // nblk*32 B
  size_t ez_off = (2048 + (size_t)nblk * 32 + 255) & ~(size_t)255;
  float* ez = (float*)(ws + ez_off);
  int useEz = (ws_size >= ez_off + (size_t)B * 16) ? 1 : 0;

  build_u_kernel<<<1, 256, 0, stream>>>(rand_params, rx0, ry0, rz0, crx0, U);
  main_kernel<<<nblk, 256, 0, stream>>>(features, (const float4*)U, ez,
                                        partials, B, useEz);
  out_kernel<<<nblk, 256, 0, stream>>>(partials, nblk, gamma, beta, W, bias,
                                       ez, features, (const float4*)U, out,
                                       B, useEz, 1.0f / (float)B);
}